// Round 7
// baseline (305.552 us; speedup 1.0000x reference)
//
#include <hip/hip_runtime.h>
#include <climits>

// Problem constants (fixed by reference setup_inputs)
constexpr int N_NODES = 50000;
constexpr int N_EDGES = 800000;
constexpr int DIM     = 128;
constexpr int DIM4    = DIM / 4;          // 32 float4 columns
constexpr float BN_EPS = 1e-5f;

// slots empty sentinel: memset byte pattern 0x7F -> 0x7F7F7F7F, which is
// larger than any edge index (800000) so atomicMin semantics are unchanged.
constexpr int EMPTY = 0x7F7F7F7F;

constexpr int PHASE1_END = 300000;        // select phase split

constexpr int NODES_PER_ITER  = 8;        // 256 threads / 32 float4-cols
constexpr int CONV_ITERS      = 3;
constexpr int NODES_PER_BLOCK = NODES_PER_ITER * CONV_ITERS;   // 24
constexpr int CONV_GRID = (N_NODES + NODES_PER_BLOCK - 1) / NODES_PER_BLOCK; // 2084

constexpr int NBUCKETS = 64;              // stats atomic spreading

// ---------------- float4 helpers ----------------
__device__ inline float4 f4min(float4 a, float4 b) {
    return make_float4(fminf(a.x,b.x), fminf(a.y,b.y), fminf(a.z,b.z), fminf(a.w,b.w));
}
__device__ inline float4 f4max(float4 a, float4 b) {
    return make_float4(fmaxf(a.x,b.x), fmaxf(a.y,b.y), fmaxf(a.z,b.z), fmaxf(a.w,b.w));
}
__device__ inline float4 f4add(float4 a, float4 b) {
    return make_float4(a.x+b.x, a.y+b.y, a.z+b.z, a.w+b.w);
}
__device__ inline float4 f4fma(float s, float4 v, float4 acc) {   // acc + s*v
    return make_float4(fmaf(s,v.x,acc.x), fmaf(s,v.y,acc.y), fmaf(s,v.z,acc.z), fmaf(s,v.w,acc.w));
}
__device__ inline int fresh_load(const int* p) {   // bypass stale per-XCD L2
    return __hip_atomic_load(p, __ATOMIC_RELAXED, __HIP_MEMORY_SCOPE_AGENT);
}

// Filtered cascaded-atomicMin selection of the 4 smallest edge indices per
// dst node, over edge range [start, start+count). Two sequential launches:
// phase 2 sees a near-final table, so the slot3 filter rejects almost all
// edges with a single read and no atomic. Monotonicity of atomicMin makes
// any observed slot3 an upper bound on its final value -> reject is safe.
__global__ void select_kernel(const int* __restrict__ dst,
                              int* __restrict__ slots,
                              int start, int count) {
    int i = blockIdx.x * blockDim.x + threadIdx.x;
    if (i >= count) return;
    int e = start + i;
    int v = dst[e];
    int cur = e;
    if (cur > fresh_load(&slots[4 * v + 3])) return;   // not in top-4
    #pragma unroll
    for (int j = 0; j < 4; ++j) {
        int old = atomicMin(&slots[4 * v + j], cur);
        if (old == EMPTY) return;            // cell was empty: insertion done
        cur = max(cur, old);                 // carry the larger value downward
        if (j < 3 && cur > fresh_load(&slots[4 * v + 3])) return;
    }
}

// slots (edge indices) -> gather row indices (src node), -1 = empty.
__global__ void remap_kernel(const int* __restrict__ slots,
                             const int* __restrict__ src,
                             int* __restrict__ srcs) {
    int i = blockIdx.x * blockDim.x + threadIdx.x;
    if (i >= 4 * N_NODES) return;
    int e = slots[i];
    srcs[i] = (e >= N_EDGES) ? -1 : src[e];   // EMPTY sentinel > N_EDGES
}

// blank_p[l] = W_l @ blank_l + b_l  (two 128x128 matvecs, blockIdx = layer)
__global__ void blank_proj_kernel(const float* __restrict__ W0, const float* __restrict__ b0,
                                  const float* __restrict__ bl0,
                                  const float* __restrict__ W1, const float* __restrict__ b1,
                                  const float* __restrict__ bl1,
                                  float* __restrict__ bp) {
    int l = blockIdx.x;
    int d = threadIdx.x;
    const float* W  = l ? W1  : W0;
    const float* b  = l ? b1  : b0;
    const float* bl = l ? bl1 : bl0;
    float s = 0.f;
    #pragma unroll 8
    for (int j = 0; j < DIM; ++j) s += W[d * DIM + j] * bl[j];
    bp[l * DIM + d] = s + b[d];
}

// ---------------------------------------------------------------------------
// Fused sort-conv + BN statistics (bucketed atomics). Identical to R5.
// Thread layout: d4 = tid&31 (float4 column), nsub = tid>>5 (8 nodes/iter).
// 24 nodes/block, 2084 blocks (8336 waves ~= device wave capacity).
// ---------------------------------------------------------------------------
__global__ __launch_bounds__(256)
void conv_stats_kernel(const float* __restrict__ x,
                       const int4* __restrict__ srcs4,    // per-node 4 gather rows
                       const float* __restrict__ bp,      // 128 floats (this layer)
                       const float* __restrict__ cw,
                       const float* __restrict__ cb,
                       const float* __restrict__ a,
                       float* __restrict__ h,
                       float* __restrict__ stats_part) {  // [NBUCKETS][256]
    const int t    = threadIdx.x;
    const int d4   = t & (DIM4 - 1);
    const int nsub = t >> 5;

    const float4* __restrict__ x4 = (const float4*)x;
    float4*       __restrict__ h4 = (float4*)h;

    const float aa = a[0];
    const float c0 = cw[0], c1 = cw[1], c2 = cw[2], c3 = cw[3];
    const float cbv = cb[0];
    const float4 bpv = ((const float4*)bp)[d4];

    float4 s  = make_float4(0.f, 0.f, 0.f, 0.f);
    float4 s2 = make_float4(0.f, 0.f, 0.f, 0.f);

    const int vbase = blockIdx.x * NODES_PER_BLOCK;
    #pragma unroll
    for (int it = 0; it < CONV_ITERS; ++it) {
        const int v = vbase + it * NODES_PER_ITER + nsub;
        if (v < N_NODES) {
            const int4 sv = srcs4[v];
            float4 m0 = (sv.x >= 0) ? x4[(size_t)sv.x * DIM4 + d4] : bpv;
            float4 m1 = (sv.y >= 0) ? x4[(size_t)sv.y * DIM4 + d4] : bpv;
            float4 m2 = (sv.z >= 0) ? x4[(size_t)sv.z * DIM4 + d4] : bpv;
            float4 m3 = (sv.w >= 0) ? x4[(size_t)sv.w * DIM4 + d4] : bpv;

            // component-wise 4-element sorting network (0,1)(2,3)(0,2)(1,3)(1,2)
            #define CSWAP4(p, q) { float4 lo = f4min(p, q); float4 hi = f4max(p, q); p = lo; q = hi; }
            CSWAP4(m0, m1); CSWAP4(m2, m3); CSWAP4(m0, m2); CSWAP4(m1, m3); CSWAP4(m1, m2);
            #undef CSWAP4

            float4 xv = x4[(size_t)v * DIM4 + d4];
            float4 hv = make_float4(cbv, cbv, cbv, cbv);
            hv = f4fma(c0, m0, hv);
            hv = f4fma(c1, m1, hv);
            hv = f4fma(c2, m2, hv);
            hv = f4fma(aa, xv, hv);
            hv = f4fma(c3, m3, hv);
            h4[(size_t)v * DIM4 + d4] = hv;

            s  = f4add(s, hv);
            s2 = f4add(s2, make_float4(hv.x*hv.x, hv.y*hv.y, hv.z*hv.z, hv.w*hv.w));
        }
    }

    // intra-wave: lane i += lane i+32 (same d4 column, different node)
    s.x  += __shfl_down(s.x, 32);  s.y  += __shfl_down(s.y, 32);
    s.z  += __shfl_down(s.z, 32);  s.w  += __shfl_down(s.w, 32);
    s2.x += __shfl_down(s2.x, 32); s2.y += __shfl_down(s2.y, 32);
    s2.z += __shfl_down(s2.z, 32); s2.w += __shfl_down(s2.w, 32);

    __shared__ float4 ls[4][32];
    __shared__ float4 ls2[4][32];
    const int wave = t >> 6;
    const int lane = t & 63;
    if (lane < 32) { ls[wave][lane] = s; ls2[wave][lane] = s2; }
    __syncthreads();
    if (t < 32) {
        float* bucket = stats_part + (size_t)(blockIdx.x & (NBUCKETS - 1)) * 256;
        float4 fs  = f4add(f4add(ls[0][t],  ls[1][t]),  f4add(ls[2][t],  ls[3][t]));
        float4 fs2 = f4add(f4add(ls2[0][t], ls2[1][t]), f4add(ls2[2][t], ls2[3][t]));
        atomicAdd(&bucket[4*t + 0], fs.x);
        atomicAdd(&bucket[4*t + 1], fs.y);
        atomicAdd(&bucket[4*t + 2], fs.z);
        atomicAdd(&bucket[4*t + 3], fs.w);
        atomicAdd(&bucket[DIM + 4*t + 0], fs2.x);
        atomicAdd(&bucket[DIM + 4*t + 1], fs2.y);
        atomicAdd(&bucket[DIM + 4*t + 2], fs2.z);
        atomicAdd(&bucket[DIM + 4*t + 3], fs2.w);
    }
}

// Sum the 64 bucket partials, finalize to mu (final[0:128]) and invstd (final[128:256]).
__global__ void reduce_finalize_kernel(const float* __restrict__ stats_part,
                                       float* __restrict__ final) {
    __shared__ float acc[256];
    int t = threadIdx.x;                 // 256 threads: t<128 sums, t>=128 sq-sums
    float s = 0.f;
    #pragma unroll 8
    for (int k = 0; k < NBUCKETS; ++k) s += stats_part[k * 256 + t];
    acc[t] = s;
    __syncthreads();
    if (t < 128) {
        constexpr float invN = 1.0f / (float)N_NODES;
        float mu = acc[t] * invN;
        float iv = rsqrtf(acc[128 + t] * invN - mu * mu + BN_EPS);
        final[t]       = mu;
        final[128 + t] = iv;
    }
}

// xout = xin + (h - mu) * invstd * g + be
__global__ void bn_apply_kernel(const float* __restrict__ xin,
                                const float* __restrict__ h,
                                const float* __restrict__ final,
                                const float* __restrict__ g,
                                const float* __restrict__ be,
                                float* __restrict__ xout) {
    int idx = blockIdx.x * blockDim.x + threadIdx.x;   // float4 index
    constexpr int TOTAL4 = N_NODES * DIM4;
    if (idx >= TOTAL4) return;
    int d4 = idx & (DIM4 - 1);

    float4 mu = ((const float4*)final)[d4];
    float4 iv = ((const float4*)(final + DIM))[d4];
    float4 hv = ((const float4*)h)[idx];
    float4 xv = ((const float4*)xin)[idx];
    float4 gv = ((const float4*)g)[d4];
    float4 bv = ((const float4*)be)[d4];

    float4 o;
    o.x = xv.x + (hv.x - mu.x) * iv.x * gv.x + bv.x;
    o.y = xv.y + (hv.y - mu.y) * iv.y * gv.y + bv.y;
    o.z = xv.z + (hv.z - mu.z) * iv.z * gv.z + bv.z;
    o.w = xv.w + (hv.w - mu.w) * iv.w * gv.w + bv.w;
    ((float4*)xout)[idx] = o;
}

extern "C" void kernel_launch(void* const* d_in, const int* in_sizes, int n_in,
                              void* d_out, int out_size, void* d_ws, size_t ws_size,
                              hipStream_t stream) {
    const float* x0  = (const float*)d_in[0];
    const int*   ei  = (const int*)d_in[1];
    const int*   src = ei;               // edge_index[0]
    const int*   dst = ei + N_EDGES;     // edge_index[1]

    const float* W[2]; const float* b[2]; const float* cw[2]; const float* cb[2];
    const float* a[2]; const float* g[2]; const float* be[2]; const float* blank[2];
    for (int i = 0; i < 2; ++i) {
        int o = 2 + 8 * i;
        W[i]     = (const float*)d_in[o + 0];
        b[i]     = (const float*)d_in[o + 1];
        cw[i]    = (const float*)d_in[o + 2];
        cb[i]    = (const float*)d_in[o + 3];
        a[i]     = (const float*)d_in[o + 4];
        g[i]     = (const float*)d_in[o + 5];
        be[i]    = (const float*)d_in[o + 6];
        blank[i] = (const float*)d_in[o + 7];
    }

    // Workspace layout (re-poisoned 0xAA each call — init everything used)
    char* ws = (char*)d_ws;
    int*   slots      = (int*)ws;                                 // 4N ints, int4/node
    int*   srcs       = slots + 4 * N_NODES;                      // 4N ints, int4/node
    float* h          = (float*)(srcs + 4 * N_NODES);             // N*DIM floats = 25.6 MB
    float* stats_part = h + (size_t)N_NODES * DIM;                // 2 * 64 * 256 floats
    float* final_     = stats_part + 2 * NBUCKETS * 256;          // 2 * 256 floats
    float* bp         = final_ + 512;                             // 256 floats (2 layers)

    float* xout = (float*)d_out;

    // ---- init via async memsets (graph-capture legal) ----
    // slots: bytes 0x7F -> EMPTY sentinel; stats partials: 0.0f
    hipMemsetAsync(slots, 0x7F, 4 * (size_t)N_NODES * sizeof(int), stream);
    hipMemsetAsync(stats_part, 0, 2 * NBUCKETS * 256 * sizeof(float), stream);

    // ---- two-phase filtered edge selection (shared by both layers) ----
    select_kernel<<<(PHASE1_END + 255) / 256, 256, 0, stream>>>(
        dst, slots, 0, PHASE1_END);
    select_kernel<<<((N_EDGES - PHASE1_END) + 255) / 256, 256, 0, stream>>>(
        dst, slots, PHASE1_END, N_EDGES - PHASE1_END);
    remap_kernel<<<(4 * N_NODES + 255) / 256, 256, 0, stream>>>(slots, src, srcs);

    blank_proj_kernel<<<2, DIM, 0, stream>>>(W[0], b[0], blank[0],
                                             W[1], b[1], blank[1], bp);

    // ---- two layers ----
    for (int l = 0; l < 2; ++l) {
        const float* xin = (l == 0) ? x0 : xout;
        float* sp = stats_part + (size_t)l * NBUCKETS * 256;
        conv_stats_kernel<<<CONV_GRID, 256, 0, stream>>>(
            xin, (const int4*)srcs, bp + l * DIM, cw[l], cb[l], a[l], h, sp);
        reduce_finalize_kernel<<<1, 256, 0, stream>>>(sp, final_ + l * 256);
        bn_apply_kernel<<<(N_NODES * DIM4 + 255) / 256, 256, 0, stream>>>(
            xin, h, final_ + l * 256, g[l], be[l], xout);
    }
}

// Round 8
// 269.687 us; speedup vs baseline: 1.1330x; 1.1330x over previous
//
#include <hip/hip_runtime.h>
#include <climits>

// Problem constants (fixed by reference setup_inputs)
constexpr int N_NODES = 50000;
constexpr int N_EDGES = 800000;
constexpr int DIM     = 128;
constexpr int DIM4    = DIM / 4;          // 32 float4 columns
constexpr float BN_EPS = 1e-5f;

// slots empty sentinel: memset byte pattern 0x7F -> 0x7F7F7F7F, which is
// larger than any edge index (800000) so atomicMin semantics are unchanged.
constexpr int EMPTY = 0x7F7F7F7F;

constexpr int NTABLES = 8;                // private selection tables (contention /8)

constexpr int NODES_PER_ITER  = 8;        // 256 threads / 32 float4-cols
constexpr int CONV_ITERS      = 3;
constexpr int NODES_PER_BLOCK = NODES_PER_ITER * CONV_ITERS;   // 24
constexpr int CONV_GRID = (N_NODES + NODES_PER_BLOCK - 1) / NODES_PER_BLOCK; // 2084

constexpr int NBUCKETS = 64;              // stats atomic spreading

// ---------------- float4 helpers ----------------
__device__ inline float4 f4min(float4 a, float4 b) {
    return make_float4(fminf(a.x,b.x), fminf(a.y,b.y), fminf(a.z,b.z), fminf(a.w,b.w));
}
__device__ inline float4 f4max(float4 a, float4 b) {
    return make_float4(fmaxf(a.x,b.x), fmaxf(a.y,b.y), fmaxf(a.z,b.z), fmaxf(a.w,b.w));
}
__device__ inline float4 f4add(float4 a, float4 b) {
    return make_float4(a.x+b.x, a.y+b.y, a.z+b.z, a.w+b.w);
}
__device__ inline float4 f4fma(float s, float4 v, float4 acc) {   // acc + s*v
    return make_float4(fmaf(s,v.x,acc.x), fmaf(s,v.y,acc.y), fmaf(s,v.z,acc.z), fmaf(s,v.w,acc.w));
}

// ---------------------------------------------------------------------------
// Privatized selection: table (blockIdx&7) receives this block's edges via
// cascaded atomicMin (sorted insert of the 4 smallest edge indices per node).
// ~2 inserts/node/table -> cascade terminates on EMPTY after ~1-2 atomics,
// and per-line contention is 1/8 of a shared table.
// ---------------------------------------------------------------------------
__global__ void select_private_kernel(const int* __restrict__ dst,
                                      int* __restrict__ tables) {
    int e = blockIdx.x * blockDim.x + threadIdx.x;
    if (e >= N_EDGES) return;
    int* __restrict__ table = tables + (size_t)(blockIdx.x & (NTABLES - 1)) * 4 * N_NODES;
    int v = dst[e];
    int cur = e;
    #pragma unroll
    for (int j = 0; j < 4; ++j) {
        int old = atomicMin(&table[4 * v + j], cur);
        if (old == EMPTY) return;            // cell was empty: insertion done
        cur = max(cur, old);                 // carry the larger value downward
    }
}

// Merge the 8 private tables (4 sorted candidates each) into the global
// top-4 per node, then map edge index -> src node row (-1 = empty slot).
// Correct because each node's global top-4 edges are each, within their own
// partition, among that partition's top-4.
__global__ void merge_remap_kernel(const int* __restrict__ tables,
                                   const int* __restrict__ src,
                                   int4* __restrict__ srcs4) {
    int v = blockIdx.x * blockDim.x + threadIdx.x;
    if (v >= N_NODES) return;

    int b0 = EMPTY, b1 = EMPTY, b2 = EMPTY, b3 = EMPTY;
    #pragma unroll
    for (int t = 0; t < NTABLES; ++t) {
        const int4 c = ((const int4*)(tables + (size_t)t * 4 * N_NODES))[v];
        #define INS(val) {                                          \
            int x_ = (val);                                         \
            if (x_ < b3) { b3 = x_;                                 \
                int tm;                                             \
                if (b3 < b2) { tm = b2; b2 = b3; b3 = tm; }         \
                if (b2 < b1) { tm = b1; b1 = b2; b2 = tm; }         \
                if (b1 < b0) { tm = b0; b0 = b1; b1 = tm; } } }
        INS(c.x); INS(c.y); INS(c.z); INS(c.w);
        #undef INS
    }
    int4 o;
    o.x = (b0 < N_EDGES) ? src[b0] : -1;
    o.y = (b1 < N_EDGES) ? src[b1] : -1;
    o.z = (b2 < N_EDGES) ? src[b2] : -1;
    o.w = (b3 < N_EDGES) ? src[b3] : -1;
    srcs4[v] = o;
}

// blank_p[l] = W_l @ blank_l + b_l  (two 128x128 matvecs, blockIdx = layer)
__global__ void blank_proj_kernel(const float* __restrict__ W0, const float* __restrict__ b0,
                                  const float* __restrict__ bl0,
                                  const float* __restrict__ W1, const float* __restrict__ b1,
                                  const float* __restrict__ bl1,
                                  float* __restrict__ bp) {
    int l = blockIdx.x;
    int d = threadIdx.x;
    const float* W  = l ? W1  : W0;
    const float* b  = l ? b1  : b0;
    const float* bl = l ? bl1 : bl0;
    float s = 0.f;
    #pragma unroll 8
    for (int j = 0; j < DIM; ++j) s += W[d * DIM + j] * bl[j];
    bp[l * DIM + d] = s + b[d];
}

// ---------------------------------------------------------------------------
// Fused sort-conv + BN statistics (bucketed atomics). Identical to R7.
// Thread layout: d4 = tid&31 (float4 column), nsub = tid>>5 (8 nodes/iter).
// 24 nodes/block, 2084 blocks (8336 waves ~= device wave capacity).
// ---------------------------------------------------------------------------
__global__ __launch_bounds__(256)
void conv_stats_kernel(const float* __restrict__ x,
                       const int4* __restrict__ srcs4,    // per-node 4 gather rows
                       const float* __restrict__ bp,      // 128 floats (this layer)
                       const float* __restrict__ cw,
                       const float* __restrict__ cb,
                       const float* __restrict__ a,
                       float* __restrict__ h,
                       float* __restrict__ stats_part) {  // [NBUCKETS][256]
    const int t    = threadIdx.x;
    const int d4   = t & (DIM4 - 1);
    const int nsub = t >> 5;

    const float4* __restrict__ x4 = (const float4*)x;
    float4*       __restrict__ h4 = (float4*)h;

    const float aa = a[0];
    const float c0 = cw[0], c1 = cw[1], c2 = cw[2], c3 = cw[3];
    const float cbv = cb[0];
    const float4 bpv = ((const float4*)bp)[d4];

    float4 s  = make_float4(0.f, 0.f, 0.f, 0.f);
    float4 s2 = make_float4(0.f, 0.f, 0.f, 0.f);

    const int vbase = blockIdx.x * NODES_PER_BLOCK;
    #pragma unroll
    for (int it = 0; it < CONV_ITERS; ++it) {
        const int v = vbase + it * NODES_PER_ITER + nsub;
        if (v < N_NODES) {
            const int4 sv = srcs4[v];
            float4 m0 = (sv.x >= 0) ? x4[(size_t)sv.x * DIM4 + d4] : bpv;
            float4 m1 = (sv.y >= 0) ? x4[(size_t)sv.y * DIM4 + d4] : bpv;
            float4 m2 = (sv.z >= 0) ? x4[(size_t)sv.z * DIM4 + d4] : bpv;
            float4 m3 = (sv.w >= 0) ? x4[(size_t)sv.w * DIM4 + d4] : bpv;

            // component-wise 4-element sorting network (0,1)(2,3)(0,2)(1,3)(1,2)
            #define CSWAP4(p, q) { float4 lo = f4min(p, q); float4 hi = f4max(p, q); p = lo; q = hi; }
            CSWAP4(m0, m1); CSWAP4(m2, m3); CSWAP4(m0, m2); CSWAP4(m1, m3); CSWAP4(m1, m2);
            #undef CSWAP4

            float4 xv = x4[(size_t)v * DIM4 + d4];
            float4 hv = make_float4(cbv, cbv, cbv, cbv);
            hv = f4fma(c0, m0, hv);
            hv = f4fma(c1, m1, hv);
            hv = f4fma(c2, m2, hv);
            hv = f4fma(aa, xv, hv);
            hv = f4fma(c3, m3, hv);
            h4[(size_t)v * DIM4 + d4] = hv;

            s  = f4add(s, hv);
            s2 = f4add(s2, make_float4(hv.x*hv.x, hv.y*hv.y, hv.z*hv.z, hv.w*hv.w));
        }
    }

    // intra-wave: lane i += lane i+32 (same d4 column, different node)
    s.x  += __shfl_down(s.x, 32);  s.y  += __shfl_down(s.y, 32);
    s.z  += __shfl_down(s.z, 32);  s.w  += __shfl_down(s.w, 32);
    s2.x += __shfl_down(s2.x, 32); s2.y += __shfl_down(s2.y, 32);
    s2.z += __shfl_down(s2.z, 32); s2.w += __shfl_down(s2.w, 32);

    __shared__ float4 ls[4][32];
    __shared__ float4 ls2[4][32];
    const int wave = t >> 6;
    const int lane = t & 63;
    if (lane < 32) { ls[wave][lane] = s; ls2[wave][lane] = s2; }
    __syncthreads();
    if (t < 32) {
        float* bucket = stats_part + (size_t)(blockIdx.x & (NBUCKETS - 1)) * 256;
        float4 fs  = f4add(f4add(ls[0][t],  ls[1][t]),  f4add(ls[2][t],  ls[3][t]));
        float4 fs2 = f4add(f4add(ls2[0][t], ls2[1][t]), f4add(ls2[2][t], ls2[3][t]));
        atomicAdd(&bucket[4*t + 0], fs.x);
        atomicAdd(&bucket[4*t + 1], fs.y);
        atomicAdd(&bucket[4*t + 2], fs.z);
        atomicAdd(&bucket[4*t + 3], fs.w);
        atomicAdd(&bucket[DIM + 4*t + 0], fs2.x);
        atomicAdd(&bucket[DIM + 4*t + 1], fs2.y);
        atomicAdd(&bucket[DIM + 4*t + 2], fs2.z);
        atomicAdd(&bucket[DIM + 4*t + 3], fs2.w);
    }
}

// Sum the 64 bucket partials, finalize to mu (final[0:128]) and invstd (final[128:256]).
__global__ void reduce_finalize_kernel(const float* __restrict__ stats_part,
                                       float* __restrict__ final) {
    __shared__ float acc[256];
    int t = threadIdx.x;                 // 256 threads: t<128 sums, t>=128 sq-sums
    float s = 0.f;
    #pragma unroll 8
    for (int k = 0; k < NBUCKETS; ++k) s += stats_part[k * 256 + t];
    acc[t] = s;
    __syncthreads();
    if (t < 128) {
        constexpr float invN = 1.0f / (float)N_NODES;
        float mu = acc[t] * invN;
        float iv = rsqrtf(acc[128 + t] * invN - mu * mu + BN_EPS);
        final[t]       = mu;
        final[128 + t] = iv;
    }
}

// xout = xin + (h - mu) * invstd * g + be
__global__ void bn_apply_kernel(const float* __restrict__ xin,
                                const float* __restrict__ h,
                                const float* __restrict__ final,
                                const float* __restrict__ g,
                                const float* __restrict__ be,
                                float* __restrict__ xout) {
    int idx = blockIdx.x * blockDim.x + threadIdx.x;   // float4 index
    constexpr int TOTAL4 = N_NODES * DIM4;
    if (idx >= TOTAL4) return;
    int d4 = idx & (DIM4 - 1);

    float4 mu = ((const float4*)final)[d4];
    float4 iv = ((const float4*)(final + DIM))[d4];
    float4 hv = ((const float4*)h)[idx];
    float4 xv = ((const float4*)xin)[idx];
    float4 gv = ((const float4*)g)[d4];
    float4 bv = ((const float4*)be)[d4];

    float4 o;
    o.x = xv.x + (hv.x - mu.x) * iv.x * gv.x + bv.x;
    o.y = xv.y + (hv.y - mu.y) * iv.y * gv.y + bv.y;
    o.z = xv.z + (hv.z - mu.z) * iv.z * gv.z + bv.z;
    o.w = xv.w + (hv.w - mu.w) * iv.w * gv.w + bv.w;
    ((float4*)xout)[idx] = o;
}

extern "C" void kernel_launch(void* const* d_in, const int* in_sizes, int n_in,
                              void* d_out, int out_size, void* d_ws, size_t ws_size,
                              hipStream_t stream) {
    const float* x0  = (const float*)d_in[0];
    const int*   ei  = (const int*)d_in[1];
    const int*   src = ei;               // edge_index[0]
    const int*   dst = ei + N_EDGES;     // edge_index[1]

    const float* W[2]; const float* b[2]; const float* cw[2]; const float* cb[2];
    const float* a[2]; const float* g[2]; const float* be[2]; const float* blank[2];
    for (int i = 0; i < 2; ++i) {
        int o = 2 + 8 * i;
        W[i]     = (const float*)d_in[o + 0];
        b[i]     = (const float*)d_in[o + 1];
        cw[i]    = (const float*)d_in[o + 2];
        cb[i]    = (const float*)d_in[o + 3];
        a[i]     = (const float*)d_in[o + 4];
        g[i]     = (const float*)d_in[o + 5];
        be[i]    = (const float*)d_in[o + 6];
        blank[i] = (const float*)d_in[o + 7];
    }

    // Workspace layout (re-poisoned 0xAA each call — init everything used)
    char* ws = (char*)d_ws;
    int*   tables     = (int*)ws;                                 // 8 * 4N ints = 6.4 MB
    int*   srcs       = tables + (size_t)NTABLES * 4 * N_NODES;   // 4N ints, int4/node
    float* h          = (float*)(srcs + 4 * N_NODES);             // N*DIM floats = 25.6 MB
    float* stats_part = h + (size_t)N_NODES * DIM;                // 2 * 64 * 256 floats
    float* final_     = stats_part + 2 * NBUCKETS * 256;          // 2 * 256 floats
    float* bp         = final_ + 512;                             // 256 floats (2 layers)

    float* xout = (float*)d_out;

    // ---- init via async memsets (graph-capture legal) ----
    hipMemsetAsync(tables, 0x7F, (size_t)NTABLES * 4 * N_NODES * sizeof(int), stream);
    hipMemsetAsync(stats_part, 0, 2 * NBUCKETS * 256 * sizeof(float), stream);

    // ---- privatized edge selection + merge (shared by both layers) ----
    select_private_kernel<<<(N_EDGES + 255) / 256, 256, 0, stream>>>(dst, tables);
    merge_remap_kernel<<<(N_NODES + 255) / 256, 256, 0, stream>>>(
        tables, src, (int4*)srcs);

    blank_proj_kernel<<<2, DIM, 0, stream>>>(W[0], b[0], blank[0],
                                             W[1], b[1], blank[1], bp);

    // ---- two layers ----
    for (int l = 0; l < 2; ++l) {
        const float* xin = (l == 0) ? x0 : xout;
        float* sp = stats_part + (size_t)l * NBUCKETS * 256;
        conv_stats_kernel<<<CONV_GRID, 256, 0, stream>>>(
            xin, (const int4*)srcs, bp + l * DIM, cw[l], cb[l], a[l], h, sp);
        reduce_finalize_kernel<<<1, 256, 0, stream>>>(sp, final_ + l * 256);
        bn_apply_kernel<<<(N_NODES * DIM4 + 255) / 256, 256, 0, stream>>>(
            xin, h, final_ + l * 256, g[l], be[l], xout);
    }
}